// Round 11
// baseline (306.750 us; speedup 1.0000x reference)
//
#include <hip/hip_runtime.h>
#include <hip/hip_fp16.h>
#include <cstdint>
#include <cstddef>

#define GLOBAL_AS __attribute__((address_space(1)))
#define LDS_AS    __attribute__((address_space(3)))

typedef __attribute__((ext_vector_type(8)))  _Float16 f16x8;
typedef __attribute__((ext_vector_type(16))) float    f32x16;

__device__ __forceinline__ void gload_lds16(const void* g, void* l) {
    __builtin_amdgcn_global_load_lds((const GLOBAL_AS void*)g,
                                     (LDS_AS void*)l, 16, 0, 0);
}

// fp16 quantizer == reference fp_quantize_ste(exp=5, sig=10): RNE + saturate.
__device__ __forceinline__ __half qcvt(float x) {
    x = fminf(fmaxf(x, -65504.f), 65504.f);
    return __float2half(x);   // v_cvt_f16_f32: RNE, subnormals handled
}

// Fused quantization of x and w (both f32 -> f16), one launch, grid-stride.
__global__ void quant_xw_f32_to_f16(const float* __restrict__ xin, int x4,
                                    const float* __restrict__ win, int w4,
                                    __half* __restrict__ xout,
                                    __half* __restrict__ wout) {
    const int stride = gridDim.x * blockDim.x;
    const int tot = x4 + w4;
    for (int i = blockIdx.x * blockDim.x + threadIdx.x; i < tot; i += stride) {
        const bool isx = (i < x4);
        const int  j   = isx ? i : i - x4;
        const float4 f = reinterpret_cast<const float4*>(isx ? xin : win)[j];
        union { __half h[4]; uint2 u; } p;
        p.h[0] = qcvt(f.x);
        p.h[1] = qcvt(f.y);
        p.h[2] = qcvt(f.z);
        p.h[3] = qcvt(f.w);
        reinterpret_cast<uint2*>(isx ? xout : wout)[j] = p.u;
    }
}

// ---------------------------------------------------------------------------
// 256x256 tile, BK=64, 8 waves (2Mx4N), 4 phases/K-tile — R7 schedule with
// mfma_f32_32x32x16_f16. ROUND 11: fixed B fragment base (wc*4096, was
// wc*2048 — waves 1..3 read wrong B columns in R10).
//
// Forward LDS map (64-row x 128-byte region, from the staging inverse swz):
//   L(row64,cb) = ((row64>>4)*2 + (cb>>6))*1024
//               + (((row64&15)*64 + (cb&63)) ^ (((row64>>3)&1)<<5))
// A frag (mm,kk): lane l holds A[R0+(l&31)][kk*16+(l>>5)*8+0..7]:
//   base = wr*8192 + (lr>>4)*2048 + (lr&15)*64 + hi*16 + b*32 (b=(lr>>3)&1),
//   + mm*4096 + (kk>>1)*1024, odd kk flips bit5 (O = E^32).
// B frag (kk): lane l holds W[C0+(l&31)][kk*16+(l>>5)*8+0..7]:
//   base = wc*4096 + (lr>>4)*2048 + same in-subtile; C0 = qb*128+wc*32.
// C/D (m74/m101): col = lane&31, row = (reg&3) + 8*(reg>>2) + 4*(lane>>5).
//
// Phases: P0=(A0,B0) reads af<-A0(8); P1=(A0,B1) reads B1(4); P2=(A1,B1)
// reads af<-A1(8); P3=(A1,B0) pre-reads next B0(4) after vmcnt(6)+barrier.
// Staging: P0: B0(t+1)->nxt  P1: A0(t+2)->cur  P2: B1(t+2)->cur  P3: A1(t+2).
// lgkm ledgers: P0 entry 4(B0') +8 -> W4 (retires B0'+mm0), W0. P1 +4 ->
// W2, W0. P2 +8 -> W4, W0. P3: issue 4, no wait (carried to next P0).
// ---------------------------------------------------------------------------
__global__ __launch_bounds__(512, 2) void gemm_f16_32x32(
    const __half* __restrict__ A, const __half* __restrict__ B,
    const float* __restrict__ bias, float* __restrict__ C,
    int M, int N, int K)
{
    __shared__ __align__(16) __half lds[2][2][2][8192];   // 128 KiB
    // layout: [buf](64KiB) [op A=0/B=1](32KiB) [half](16KiB) data

    const int tid  = threadIdx.x;
    const int lane = tid & 63;
    const int wid  = tid >> 6;     // 8 waves
    const int wr   = wid >> 2;     // 0..1 (M)
    const int wc   = wid & 3;      // 0..3 (N)
    const int lr   = lane & 31;    // row/col within 32-frag
    const int hi   = lane >> 5;    // k-half selector

    // bijective XCD swizzle (m204)
    const int nwg = gridDim.x;
    const int qq = nwg >> 3, rr = nwg & 7;
    const int xcd = blockIdx.x & 7, idx = blockIdx.x >> 3;
    const int wgid = (xcd < rr ? xcd * (qq + 1)
                               : rr * (qq + 1) + (xcd - rr) * qq) + idx;
    const int nbn = N >> 8;
    const int tile_m = (wgid / nbn) << 8;
    const int tile_n = (wgid % nbn) << 8;

    // ---- staging source coords (inverse of LDS swizzle, per thread) ----
    const int wbyte = (lane * 16) ^ (((lane >> 5) & 1) << 5);
    const int srow  = ((wid >> 1) << 4) + (wbyte >> 6);   // 0..63
    const int scb   = ((wid & 1) << 6) + (wbyte & 63);    // col byte 0..127
    const char* gA0 = (const char*)A + (size_t)(tile_m + srow) * K * 2 + scb;
    const char* gB0 = (const char*)B + (size_t)(tile_n + srow) * K * 2 + scb;
    const size_t rstep = (size_t)64  * K * 2;   // +64 rows
    const size_t hstep = (size_t)128 * K * 2;   // +1 half (128 rows)
    const int ldst = tid * 16;                  // linear LDS dest byte

    // ---- fragment-read LDS base addresses (st_16x32 swizzled) ----
    const uint32_t laneE = (uint32_t)((lr >> 4) * 2048 + (lr & 15) * 64
                                      + hi * 16 + (((lr >> 3) & 1) << 5));
    const uint32_t lds0 = (uint32_t)(size_t)(LDS_AS const char*)&lds[0][0][0][0];
    const uint32_t aE0 = lds0 + (uint32_t)(wr * 8192) + laneE;
    const uint32_t aO0 = aE0 ^ 32u;
    const uint32_t aE1 = aE0 + 65536u;
    const uint32_t aO1 = aE1 ^ 32u;
    const uint32_t bE0 = lds0 + 32768u + (uint32_t)(wc * 4096) + laneE;  // FIXED
    const uint32_t bO0 = bE0 ^ 32u;
    const uint32_t bE1 = bE0 + 65536u;
    const uint32_t bO1 = bE1 ^ 32u;

    f32x16 acc[2][2][2];   // [qa][qb][mm] -> 128 acc regs
#pragma unroll
    for (int qa = 0; qa < 2; ++qa)
#pragma unroll
        for (int qb = 0; qb < 2; ++qb)
#pragma unroll
            for (int mm = 0; mm < 2; ++mm)
#pragma unroll
                for (int e = 0; e < 16; ++e)
                    acc[qa][qb][mm][e] = 0.f;

    f16x8 af[2][4];    // A fragments [mm][kk] of current half
    f16x8 bfP[4];      // B set ping [kk]
    f16x8 bfQ[4];      // B set pong [kk]

#define STAGE_A(bufi, h, kt) do {                                          \
        char* l_ = (char*)(&lds[bufi][0][h][0]) + ldst;                    \
        const char* g_ = gA0 + (size_t)(kt) * 128 + ((h) ? hstep : 0);     \
        gload_lds16(g_, l_);                                               \
        gload_lds16(g_ + rstep, l_ + 8192);                                \
    } while (0)

#define STAGE_B(bufi, h, kt) do {                                          \
        char* l_ = (char*)(&lds[bufi][1][h][0]) + ldst;                    \
        const char* g_ = gB0 + (size_t)(kt) * 128 + ((h) ? hstep : 0);     \
        gload_lds16(g_, l_);                                               \
        gload_lds16(g_ + rstep, l_ + 8192);                                \
    } while (0)

// inline-asm ds_read_b128, base VGPR + constant offset via %c
#define DSR(dst, base, OFF)                                                \
    asm volatile("ds_read_b128 %0, %1 offset:%c2"                          \
                 : "=v"(dst) : "v"(base), "i"(OFF))

// 8 A reads: mm0 kk0..3 first (retired by WAITL(4)), then mm1 kk0..3
#define LDGA(E, O, Q) do {                                                 \
        DSR(af[0][0], E, (Q)*16384 + 0);                                   \
        DSR(af[0][1], O, (Q)*16384 + 0);                                   \
        DSR(af[0][2], E, (Q)*16384 + 1024);                                \
        DSR(af[0][3], O, (Q)*16384 + 1024);                                \
        DSR(af[1][0], E, (Q)*16384 + 4096);                                \
        DSR(af[1][1], O, (Q)*16384 + 4096);                                \
        DSR(af[1][2], E, (Q)*16384 + 5120);                                \
        DSR(af[1][3], O, (Q)*16384 + 5120);                                \
    } while (0)

// 4 B reads: kk0..3
#define LDGB(dst, E, O, HB) do {                                           \
        DSR(dst[0], E, (HB)*16384 + 0);                                    \
        DSR(dst[1], O, (HB)*16384 + 0);                                    \
        DSR(dst[2], E, (HB)*16384 + 1024);                                 \
        DSR(dst[3], O, (HB)*16384 + 1024);                                 \
    } while (0)

#define MFMA32(A8, B8, ACC)                                                \
    ACC = __builtin_amdgcn_mfma_f32_32x32x16_f16(A8, B8, ACC, 0, 0, 0)

// 4 MFMAs: one mm, kk 0..3
#define MMA4(QA, QB, MM, BF) do {                                          \
        __builtin_amdgcn_s_setprio(1);                                     \
        MFMA32(af[MM][0], BF[0], acc[QA][QB][MM]);                         \
        MFMA32(af[MM][1], BF[1], acc[QA][QB][MM]);                         \
        MFMA32(af[MM][2], BF[2], acc[QA][QB][MM]);                         \
        MFMA32(af[MM][3], BF[3], acc[QA][QB][MM]);                         \
        __builtin_amdgcn_s_setprio(0);                                     \
    } while (0)

// 4 MFMAs: both mm, two kk values (for B-gated split)
#define MMA_KK2(QA, QB, K0, K1, BF) do {                                   \
        __builtin_amdgcn_s_setprio(1);                                     \
        MFMA32(af[0][K0], BF[K0], acc[QA][QB][0]);                         \
        MFMA32(af[1][K0], BF[K0], acc[QA][QB][1]);                         \
        MFMA32(af[0][K1], BF[K1], acc[QA][QB][0]);                         \
        MFMA32(af[1][K1], BF[K1], acc[QA][QB][1]);                         \
        __builtin_amdgcn_s_setprio(0);                                     \
    } while (0)

// counted lgkm wait + scheduler fence (rule #18)
#define WAITL(NLIT)                                                        \
    asm volatile("s_waitcnt lgkmcnt(" NLIT ")");                           \
    __builtin_amdgcn_sched_barrier(0)

#define BARS()                                                             \
    __builtin_amdgcn_s_barrier();                                          \
    __builtin_amdgcn_sched_barrier(0)

#define TILE_FULL(AEc, AOc, BEc, BOc, BEn, BOn, CURB, NXTB, kt, SU, SV)    \
    /* P0: MFMA(A0,B0=SU); af<-A0; stage B0(t+1)->nxt */                   \
    LDGA(AEc, AOc, 0); STAGE_B(NXTB, 0, (kt) + 1);                         \
    WAITL("4"); MMA4(0, 0, 0, SU);                                         \
    WAITL("0"); MMA4(0, 0, 1, SU);                                         \
    BARS();                                                                \
    /* P1: MFMA(A0,B1=SV); B1 reads; stage A0(t+2)->cur */                 \
    LDGB(SV, BEc, BOc, 1); STAGE_A(CURB, 0, (kt) + 2);                     \
    WAITL("2"); MMA_KK2(0, 1, 0, 1, SV);                                   \
    WAITL("0"); MMA_KK2(0, 1, 2, 3, SV);                                   \
    BARS();                                                                \
    /* P2: MFMA(A1,B1); af<-A1; stage B1(t+2)->cur */                      \
    LDGA(AEc, AOc, 1); STAGE_B(CURB, 1, (kt) + 2);                         \
    WAITL("4"); MMA4(1, 1, 0, SV);                                         \
    WAITL("0"); MMA4(1, 1, 1, SV);                                         \
    BARS();                                                                \
    /* P3: stage A1(t+2); confirm t+1; pre-read B0(t+1)->SV; MFMA(A1,B0) */\
    STAGE_A(CURB, 1, (kt) + 2);                                            \
    asm volatile("s_waitcnt vmcnt(6)");                                    \
    BARS();                                                                \
    LDGB(SV, BEn, BOn, 0);                                                 \
    __builtin_amdgcn_sched_barrier(0);                                     \
    MMA4(1, 0, 0, SU); MMA4(1, 0, 1, SU);                                  \
    BARS();

    // ---- prologue: stage tile0 fully + tile1 (A0,B1,A1); B0(1) in-loop ----
    STAGE_A(0, 0, 0); STAGE_B(0, 0, 0); STAGE_B(0, 1, 0); STAGE_A(0, 1, 0);
    STAGE_A(1, 0, 1); STAGE_B(1, 1, 1); STAGE_A(1, 1, 1);
    asm volatile("s_waitcnt vmcnt(6)");   // tile0 fully arrived
    BARS();
    LDGB(bfP, bE0, bO0, 0);               // B0(0) -> P (4 carried)
    __builtin_amdgcn_sched_barrier(0);

    const int nt = K >> 6;              // even, >= 4 (guarded by launcher)
    for (int kt = 0; kt + 3 < nt; kt += 2) {
        TILE_FULL(aE0, aO0, bE0, bO0, bE1, bO1, 0, 1, kt,     bfP, bfQ);
        TILE_FULL(aE1, aO1, bE1, bO1, bE0, bO0, 1, 0, kt + 1, bfQ, bfP);
    }

    // ---- tile nt-2 (buf0, SU=P, SV=Q): stage only B0(nt-1) ----
    LDGA(aE0, aO0, 0); STAGE_B(1, 0, nt - 1);
    WAITL("4"); MMA4(0, 0, 0, bfP);
    WAITL("0"); MMA4(0, 0, 1, bfP);
    BARS();
    LDGB(bfQ, bE0, bO0, 1);
    WAITL("2"); MMA_KK2(0, 1, 0, 1, bfQ);
    WAITL("0"); MMA_KK2(0, 1, 2, 3, bfQ);
    BARS();
    LDGA(aE0, aO0, 1);
    WAITL("4"); MMA4(1, 1, 0, bfQ);
    WAITL("0"); MMA4(1, 1, 1, bfQ);
    BARS();
    asm volatile("s_waitcnt vmcnt(0)");
    BARS();
    LDGB(bfQ, bE1, bO1, 0);               // B0(nt-1) -> Q
    __builtin_amdgcn_sched_barrier(0);
    MMA4(1, 0, 0, bfP); MMA4(1, 0, 1, bfP);
    BARS();

    // ---- tile nt-1 (buf1, SU=Q, SV=P): pure compute ----
    LDGA(aE1, aO1, 0);
    WAITL("4"); MMA4(0, 0, 0, bfQ);
    WAITL("0"); MMA4(0, 0, 1, bfQ);
    BARS();
    LDGB(bfP, bE1, bO1, 1);
    WAITL("2"); MMA_KK2(0, 1, 0, 1, bfP);
    WAITL("0"); MMA_KK2(0, 1, 2, 3, bfP);
    BARS();
    LDGA(aE1, aO1, 1);
    WAITL("4"); MMA4(1, 1, 0, bfP);
    WAITL("0"); MMA4(1, 1, 1, bfP);
    BARS();
    MMA4(1, 0, 0, bfQ); MMA4(1, 0, 1, bfQ);

    // ---- epilogue: 32x32 C/D layout (m74/m101): col=lane&31,
    //      row = (reg&3) + 8*(reg>>2) + 4*(lane>>5). bias fp16-quantized. ----
    float bv[2];
#pragma unroll
    for (int qb = 0; qb < 2; ++qb)
        bv[qb] = __half2float(qcvt(bias[tile_n + qb * 128 + wc * 32 + lr]));

#pragma unroll
    for (int qa = 0; qa < 2; ++qa)
#pragma unroll
        for (int qb = 0; qb < 2; ++qb)
#pragma unroll
            for (int mm = 0; mm < 2; ++mm) {
                const int rowb = tile_m + qa * 128 + wr * 64 + mm * 32 + 4 * hi;
                const int col  = tile_n + qb * 128 + wc * 32 + lr;
#pragma unroll
                for (int g = 0; g < 4; ++g)
#pragma unroll
                    for (int s = 0; s < 4; ++s)
                        C[(size_t)(rowb + g * 8 + s) * N + col] =
                            acc[qa][qb][mm][g * 4 + s] + bv[qb];
            }

#undef STAGE_A
#undef STAGE_B
#undef DSR
#undef LDGA
#undef LDGB
#undef MFMA32
#undef MMA4
#undef MMA_KK2
#undef WAITL
#undef BARS
#undef TILE_FULL
}

// ---------------------------------------------------------------------------
// Insurance fallback (shape or ws mismatch): fused naive, slow but correct.
// ---------------------------------------------------------------------------
__global__ void qat_gemm_naive(const float* __restrict__ A,
                               const float* __restrict__ B,
                               const float* __restrict__ bias,
                               float* __restrict__ C, int M, int N, int K) {
    const int col = blockIdx.x * blockDim.x + threadIdx.x;
    const int row = blockIdx.y;
    if (col >= N || row >= M) return;
    float s = 0.f;
    for (int k = 0; k < K; ++k) {
        float a = __half2float(qcvt(A[(size_t)row * K + k]));
        float b = __half2float(qcvt(B[(size_t)col * K + k]));
        s += a * b;
    }
    C[(size_t)row * N + col] = s + __half2float(qcvt(bias[col]));
}

// ---------------------------------------------------------------------------
extern "C" void kernel_launch(void* const* d_in, const int* in_sizes, int n_in,
                              void* d_out, int out_size, void* d_ws,
                              size_t ws_size, hipStream_t stream) {
    const float* x = (const float*)d_in[0];
    const float* w = (const float*)d_in[1];
    const float* b = (const float*)d_in[2];
    float* out = (float*)d_out;

    const int xn = in_sizes[0];     // M*K
    const int wn = in_sizes[1];     // N*K
    const int N  = in_sizes[2];     // 4096
    const int K  = wn / N;          // 4096
    const int M  = xn / K;          // 8192

    const size_t need = (size_t)(xn + wn) * sizeof(__half);
    const bool ok = (M % 256 == 0) && (N % 256 == 0) &&
                    (K % 128 == 0) && (K >= 256);

    if (ws_size >= need && ok) {
        __half* xq = (__half*)d_ws;
        __half* wq = xq + xn;

        const int x4 = xn / 4, w4 = wn / 4;
        int blk = ((x4 + w4) + 255) / 256; if (blk > 2048) blk = 2048;
        quant_xw_f32_to_f16<<<blk, 256, 0, stream>>>(x, x4, w, w4, xq, wq);

        dim3 grid((M / 256) * (N / 256));
        gemm_f16_32x32<<<grid, 512, 0, stream>>>(xq, wq, b, out, M, N, K);
    } else {
        dim3 grid((N + 255) / 256, M);
        qat_gemm_naive<<<grid, 256, 0, stream>>>(x, w, b, out, M, N, K);
    }
}

// Round 12
// 279.828 us; speedup vs baseline: 1.0962x; 1.0962x over previous
//
#include <hip/hip_runtime.h>
#include <hip/hip_fp16.h>
#include <cstdint>
#include <cstddef>

#define GLOBAL_AS __attribute__((address_space(1)))
#define LDS_AS    __attribute__((address_space(3)))

typedef __attribute__((ext_vector_type(8))) _Float16 f16x8;
typedef __attribute__((ext_vector_type(4))) float    f32x4;

__device__ __forceinline__ void gload_lds16(const void* g, void* l) {
    __builtin_amdgcn_global_load_lds((const GLOBAL_AS void*)g,
                                     (LDS_AS void*)l, 16, 0, 0);
}

// fp16 quantizer == reference fp_quantize_ste(exp=5, sig=10): RNE + saturate.
__device__ __forceinline__ __half qcvt(float x) {
    x = fminf(fmaxf(x, -65504.f), 65504.f);
    return __float2half(x);   // v_cvt_f16_f32: RNE, subnormals handled
}

// Fused quantization of x and w (both f32 -> f16), one launch, grid-stride.
__global__ void quant_xw_f32_to_f16(const float* __restrict__ xin, int x4,
                                    const float* __restrict__ win, int w4,
                                    __half* __restrict__ xout,
                                    __half* __restrict__ wout) {
    const int stride = gridDim.x * blockDim.x;
    const int tot = x4 + w4;
    for (int i = blockIdx.x * blockDim.x + threadIdx.x; i < tot; i += stride) {
        const bool isx = (i < x4);
        const int  j   = isx ? i : i - x4;
        const float4 f = reinterpret_cast<const float4*>(isx ? xin : win)[j];
        union { __half h[4]; uint2 u; } p;
        p.h[0] = qcvt(f.x);
        p.h[1] = qcvt(f.y);
        p.h[2] = qcvt(f.z);
        p.h[3] = qcvt(f.w);
        reinterpret_cast<uint2*>(isx ? xout : wout)[j] = p.u;
    }
}

// ---------------------------------------------------------------------------
// 256x256 tile, BK=64, 8 waves (2Mx4N), 4 phases/K-tile — R7 schedule
// (best verified: 237.5 us GEMM, 0 bank conflicts, MfmaUtil 54.5%).
// ROUND 12: minimal scheduler pinning (m141 lesson). sched_barrier(0) kept
// ONLY after counted lgkm waits that gate dependent MFMAs (rule #18);
// removed after s_barriers and between P3's B0' pre-read and its MFMA
// cluster (those reads are independent of the cluster — let them interleave).
//
// Phases: P0=(A0,B0) reads af<-A0(8); P1=(A0,B1) reads B1(4); P2=(A1,B1)
// reads af<-A1(8); P3=(A1,B0) pre-reads next B0(4) after vmcnt(6)+barrier.
// Staging: P0: B0(t+1)->nxt  P1: A0(t+2)->cur  P2: B1(t+2)->cur  P3: A1(t+2).
// lgkm ledgers (in-order DS): P0 entry 4(B0') +8 -> W4/W0. P1 +4 -> W2/W0.
// P2 +8 -> W4/W0. P3: issue 4, no wait (carried to next P0).
// vmcnt: 8 staging ops/tile; vmcnt(6)@P3 retires through all of tile t+1.
// WAR: every phase ends with W0 before its barrier; the STAGE overwriting a
// region is always issued after the barrier that follows the region's reads.
// ---------------------------------------------------------------------------
__global__ __launch_bounds__(512, 2) void gemm_f16_8phase(
    const __half* __restrict__ A, const __half* __restrict__ B,
    const float* __restrict__ bias, float* __restrict__ C,
    int M, int N, int K)
{
    __shared__ __align__(16) __half lds[2][2][2][8192];   // 128 KiB
    // layout: [buf](64KiB) [op A=0/B=1](32KiB) [half](16KiB) data

    const int tid  = threadIdx.x;
    const int lane = tid & 63;
    const int wid  = tid >> 6;     // 8 waves
    const int wr   = wid >> 2;     // 0..1 (M)
    const int wc   = wid & 3;      // 0..3 (N)
    const int fr   = lane & 15;
    const int fq   = lane >> 4;

    // bijective XCD swizzle (m204)
    const int nwg = gridDim.x;
    const int qq = nwg >> 3, rr = nwg & 7;
    const int xcd = blockIdx.x & 7, idx = blockIdx.x >> 3;
    const int wgid = (xcd < rr ? xcd * (qq + 1)
                               : rr * (qq + 1) + (xcd - rr) * qq) + idx;
    const int nbn = N >> 8;
    const int tile_m = (wgid / nbn) << 8;
    const int tile_n = (wgid % nbn) << 8;

    // ---- staging source coords (inverse of LDS swizzle, per thread) ----
    const int wbyte = (lane * 16) ^ (((lane >> 5) & 1) << 5);
    const int srow  = ((wid >> 1) << 4) + (wbyte >> 6);   // 0..63
    const int scb   = ((wid & 1) << 6) + (wbyte & 63);    // col byte 0..127
    const char* gA0 = (const char*)A + (size_t)(tile_m + srow) * K * 2 + scb;
    const char* gB0 = (const char*)B + (size_t)(tile_n + srow) * K * 2 + scb;
    const size_t rstep = (size_t)64  * K * 2;   // +64 rows
    const size_t hstep = (size_t)128 * K * 2;   // +1 half (128 rows)
    const int ldst = tid * 16;                  // linear LDS dest byte

    // ---- fragment-read LDS byte addresses (st_16x32 swizzled) ----
    const int woff = (fr * 64 + fq * 16) ^ (((fr >> 3) & 1) << 5);
    const uint32_t lds0 = (uint32_t)(size_t)(LDS_AS const char*)&lds[0][0][0][0];
    const uint32_t aBase = lds0 + (uint32_t)(wr * 8192 + woff);
    const uint32_t bBase = lds0 + 32768u + (uint32_t)(wc * 4096 + woff);

    f32x4 acc[2][2][4][2];
#pragma unroll
    for (int qa = 0; qa < 2; ++qa)
#pragma unroll
        for (int qb = 0; qb < 2; ++qb)
#pragma unroll
            for (int m = 0; m < 4; ++m)
#pragma unroll
                for (int n = 0; n < 2; ++n)
                    acc[qa][qb][m][n] = (f32x4){0.f, 0.f, 0.f, 0.f};

    f16x8 af[4][2];    // A fragments of the current half
    f16x8 bfP[2][2];   // B set ping
    f16x8 bfQ[2][2];   // B set pong

#define STAGE_A(bufi, h, kt) do {                                          \
        char* l_ = (char*)(&lds[bufi][0][h][0]) + ldst;                    \
        const char* g_ = gA0 + (size_t)(kt) * 128 + ((h) ? hstep : 0);     \
        gload_lds16(g_, l_);                                               \
        gload_lds16(g_ + rstep, l_ + 8192);                                \
    } while (0)

#define STAGE_B(bufi, h, kt) do {                                          \
        char* l_ = (char*)(&lds[bufi][1][h][0]) + ldst;                    \
        const char* g_ = gB0 + (size_t)(kt) * 128 + ((h) ? hstep : 0);     \
        gload_lds16(g_, l_);                                               \
        gload_lds16(g_ + rstep, l_ + 8192);                                \
    } while (0)

// inline-asm ds_read_b128 (volatile: program order among volatiles kept)
#define DSR(dst, addr, OFF)                                                \
    asm volatile("ds_read_b128 %0, %1 offset:" OFF                         \
                 : "=v"(dst) : "v"(addr))

// one A quarter: 2 reads (af[mm][0], af[mm][1])
#define LDGA_Q(bufi, qa, mm) do {                                          \
        const uint32_t a_ = aBase + (bufi) * 65536u + (qa) * 16384u        \
                            + (mm) * 2048u;                                \
        DSR(af[mm][0], a_, "0"); DSR(af[mm][1], a_, "1024");               \
    } while (0)

#define LDGA(bufi, qa) do {                                                \
        LDGA_Q(bufi, qa, 0); LDGA_Q(bufi, qa, 1);                          \
        LDGA_Q(bufi, qa, 2); LDGA_Q(bufi, qa, 3);                          \
    } while (0)

#define LDGB(dst, bufi, hb) do {                                           \
        const uint32_t b_ = bBase + (bufi) * 65536u + (hb) * 16384u;       \
        DSR(dst[0][0], b_, "0");    DSR(dst[0][1], b_, "1024");            \
        DSR(dst[1][0], b_, "2048"); DSR(dst[1][1], b_, "3072");            \
    } while (0)

#define MMA_PAIR(qa, qb, mm, nn, BF)                                       \
    acc[qa][qb][mm][nn] = __builtin_amdgcn_mfma_f32_16x16x32_f16(          \
        af[mm][0], BF[nn][0], acc[qa][qb][mm][nn], 0, 0, 0);               \
    acc[qa][qb][mm][nn] = __builtin_amdgcn_mfma_f32_16x16x32_f16(          \
        af[mm][1], BF[nn][1], acc[qa][qb][mm][nn], 0, 0, 0);

#define MMA_M01(qa, qb, BF)                                                \
    __builtin_amdgcn_s_setprio(1);                                         \
    MMA_PAIR(qa, qb, 0, 0, BF) MMA_PAIR(qa, qb, 0, 1, BF)                  \
    MMA_PAIR(qa, qb, 1, 0, BF) MMA_PAIR(qa, qb, 1, 1, BF)                  \
    __builtin_amdgcn_s_setprio(0);

#define MMA_M23(qa, qb, BF)                                                \
    __builtin_amdgcn_s_setprio(1);                                         \
    MMA_PAIR(qa, qb, 2, 0, BF) MMA_PAIR(qa, qb, 2, 1, BF)                  \
    MMA_PAIR(qa, qb, 3, 0, BF) MMA_PAIR(qa, qb, 3, 1, BF)                  \
    __builtin_amdgcn_s_setprio(0);

#define MMA_N0(qa, qb, BF)                                                 \
    __builtin_amdgcn_s_setprio(1);                                         \
    MMA_PAIR(qa, qb, 0, 0, BF) MMA_PAIR(qa, qb, 1, 0, BF)                  \
    MMA_PAIR(qa, qb, 2, 0, BF) MMA_PAIR(qa, qb, 3, 0, BF)                  \
    __builtin_amdgcn_s_setprio(0);

#define MMA_N1(qa, qb, BF)                                                 \
    __builtin_amdgcn_s_setprio(1);                                         \
    MMA_PAIR(qa, qb, 0, 1, BF) MMA_PAIR(qa, qb, 1, 1, BF)                  \
    MMA_PAIR(qa, qb, 2, 1, BF) MMA_PAIR(qa, qb, 3, 1, BF)                  \
    __builtin_amdgcn_s_setprio(0);

#define MMA_FULL(qa, qb, BF)                                               \
    MMA_M01(qa, qb, BF) MMA_M23(qa, qb, BF)

// counted lgkm wait + scheduler fence (rule #18 — REQUIRED here)
#define WAITL(NLIT)                                                        \
    asm volatile("s_waitcnt lgkmcnt(" NLIT ")");                           \
    __builtin_amdgcn_sched_barrier(0)

// bare barrier — no sched_barrier (m141: blanket pinning hurts)
#define BARS()                                                             \
    __builtin_amdgcn_s_barrier()

#define TILE_FULL(cur, nxt, kt, B0S, B1S)                                  \
    /* P0: MFMA(A0,B0) | read af<-A0(t) | stage B0(t+1)->nxt */            \
    LDGA(cur, 0); STAGE_B(nxt, 0, (kt) + 1);                               \
    WAITL("4"); MMA_M01(0, 0, B0S);                                        \
    WAITL("0"); MMA_M23(0, 0, B0S);                                        \
    BARS();                                                                \
    /* P1: MFMA(A0,B1) | read B1(t) | stage A0(t+2)->cur */                \
    LDGB(B1S, cur, 1); STAGE_A(cur, 0, (kt) + 2);                          \
    WAITL("2"); MMA_N0(0, 1, B1S);                                         \
    WAITL("0"); MMA_N1(0, 1, B1S);                                         \
    BARS();                                                                \
    /* P2: MFMA(A1,B1) | read af<-A1(t) | stage B1(t+2)->cur */            \
    LDGA(cur, 1); STAGE_B(cur, 1, (kt) + 2);                               \
    WAITL("4"); MMA_M01(1, 1, B1S);                                        \
    WAITL("0"); MMA_M23(1, 1, B1S);                                        \
    BARS();                                                                \
    /* P3: MFMA(A1,B0) | stage A1(t+2)->cur | confirm t+1 | read B0(t+1) */\
    STAGE_A(cur, 1, (kt) + 2);                                             \
    asm volatile("s_waitcnt vmcnt(6)");                                    \
    BARS();                                                                \
    LDGB(B1S, nxt, 0);                                                     \
    MMA_FULL(1, 0, B0S);                                                   \
    BARS();

    // ---- prologue: stage tile0 fully + tile1 (A0,B1,A1); B0(1) in-loop ----
    STAGE_A(0, 0, 0); STAGE_B(0, 0, 0); STAGE_B(0, 1, 0); STAGE_A(0, 1, 0);
    STAGE_A(1, 0, 1); STAGE_B(1, 1, 1); STAGE_A(1, 1, 1);
    asm volatile("s_waitcnt vmcnt(6)");   // tile0 arrived (own ledger)
    BARS();                               // collective arrival
    LDGB(bfP, 0, 0);                      // tile0 B0 -> bfP (4 outstanding)

    const int nt = K >> 6;              // even, >= 4 (guarded by launcher)
    for (int kt = 0; kt + 3 < nt; kt += 2) {
        TILE_FULL(0, 1, kt,     bfP, bfQ);
        TILE_FULL(1, 0, kt + 1, bfQ, bfP);
    }

    // ---- tile nt-2 (buf0, B0S=bfP): stage only B0(nt-1); drain at P3 ----
    LDGA(0, 0); STAGE_B(1, 0, nt - 1);
    WAITL("4"); MMA_M01(0, 0, bfP);
    WAITL("0"); MMA_M23(0, 0, bfP);
    BARS();
    LDGB(bfQ, 0, 1);
    WAITL("2"); MMA_N0(0, 1, bfQ);
    WAITL("0"); MMA_N1(0, 1, bfQ);
    BARS();
    LDGA(0, 1);
    WAITL("4"); MMA_M01(1, 1, bfQ);
    WAITL("0"); MMA_M23(1, 1, bfQ);
    BARS();
    asm volatile("s_waitcnt vmcnt(0)");
    BARS();
    LDGB(bfQ, 1, 0);                      // B0(nt-1) -> bfQ
    MMA_FULL(1, 0, bfP);
    BARS();

    // ---- tile nt-1 (buf1, B0S=bfQ): pure compute ----
    LDGA(1, 0);
    WAITL("4"); MMA_M01(0, 0, bfQ);
    WAITL("0"); MMA_M23(0, 0, bfQ);
    BARS();
    LDGB(bfP, 1, 1);
    WAITL("2"); MMA_N0(0, 1, bfP);
    WAITL("0"); MMA_N1(0, 1, bfP);
    BARS();
    LDGA(1, 1);
    WAITL("4"); MMA_M01(1, 1, bfP);
    WAITL("0"); MMA_M23(1, 1, bfP);
    BARS();
    MMA_FULL(1, 0, bfQ);

    // ---- epilogue: C/D layout col=lane&15, row=fq*4+reg (m89-verified) ----
    float bv[2][2];
#pragma unroll
    for (int qb = 0; qb < 2; ++qb)
#pragma unroll
        for (int n = 0; n < 2; ++n)
            bv[qb][n] = __half2float(qcvt(
                bias[tile_n + qb * 128 + wc * 32 + n * 16 + fr]));

#pragma unroll
    for (int qa = 0; qa < 2; ++qa)
#pragma unroll
        for (int qb = 0; qb < 2; ++qb)
#pragma unroll
            for (int m = 0; m < 4; ++m)
#pragma unroll
                for (int n = 0; n < 2; ++n) {
                    const int col = tile_n + qb * 128 + wc * 32 + n * 16 + fr;
                    const int rowb = tile_m + qa * 128 + wr * 64 + m * 16 + fq * 4;
#pragma unroll
                    for (int r = 0; r < 4; ++r)
                        C[(size_t)(rowb + r) * N + col] =
                            acc[qa][qb][m][n][r] + bv[qb][n];
                }

#undef STAGE_A
#undef STAGE_B
#undef DSR
#undef LDGA_Q
#undef LDGA
#undef LDGB
#undef MMA_PAIR
#undef MMA_M01
#undef MMA_M23
#undef MMA_N0
#undef MMA_N1
#undef MMA_FULL
#undef WAITL
#undef BARS
#undef TILE_FULL
}

// ---------------------------------------------------------------------------
// Insurance fallback (shape or ws mismatch): fused naive, slow but correct.
// ---------------------------------------------------------------------------
__global__ void qat_gemm_naive(const float* __restrict__ A,
                               const float* __restrict__ B,
                               const float* __restrict__ bias,
                               float* __restrict__ C, int M, int N, int K) {
    const int col = blockIdx.x * blockDim.x + threadIdx.x;
    const int row = blockIdx.y;
    if (col >= N || row >= M) return;
    float s = 0.f;
    for (int k = 0; k < K; ++k) {
        float a = __half2float(qcvt(A[(size_t)row * K + k]));
        float b = __half2float(qcvt(B[(size_t)col * K + k]));
        s += a * b;
    }
    C[(size_t)row * N + col] = s + __half2float(qcvt(bias[col]));
}

// ---------------------------------------------------------------------------
extern "C" void kernel_launch(void* const* d_in, const int* in_sizes, int n_in,
                              void* d_out, int out_size, void* d_ws,
                              size_t ws_size, hipStream_t stream) {
    const float* x = (const float*)d_in[0];
    const float* w = (const float*)d_in[1];
    const float* b = (const float*)d_in[2];
    float* out = (float*)d_out;

    const int xn = in_sizes[0];     // M*K
    const int wn = in_sizes[1];     // N*K
    const int N  = in_sizes[2];     // 4096
    const int K  = wn / N;          // 4096
    const int M  = xn / K;          // 8192

    const size_t need = (size_t)(xn + wn) * sizeof(__half);
    const bool ok = (M % 256 == 0) && (N % 256 == 0) &&
                    (K % 128 == 0) && (K >= 256);

    if (ws_size >= need && ok) {
        __half* xq = (__half*)d_ws;
        __half* wq = xq + xn;

        const int x4 = xn / 4, w4 = wn / 4;
        int blk = ((x4 + w4) + 255) / 256; if (blk > 2048) blk = 2048;
        quant_xw_f32_to_f16<<<blk, 256, 0, stream>>>(x, x4, w, w4, xq, wq);

        dim3 grid((M / 256) * (N / 256));
        gemm_f16_8phase<<<grid, 512, 0, stream>>>(xq, wq, b, out, M, N, K);
    } else {
        dim3 grid((N + 255) / 256, M);
        qat_gemm_naive<<<grid, 256, 0, stream>>>(x, w, b, out, M, N, K);
    }
}